// Round 12
// baseline (355.766 us; speedup 1.0000x reference)
//
#include <hip/hip_runtime.h>
#include <hip/hip_bf16.h>
#include <math.h>

#define D 64
#define K 1024
#define N_VEC 262144  // 64*64*64
#define FLAG_CAP 65536
#define T_BIAS 144.0f
// Accumulate T = x.c - 0.5|c|^2 at natural magnitude (|acc| <~ 6, adds round
// at ~2.4e-7), then add T_BIAS=144 ONCE per element. T' in (137,151) within
// window [128,160): bits[31:22] constant (exp 134, mantissa bit22=0), so
// packed = (bits<<10)|(1023-code) is exact order-preserving u32 with
// lowest-code tie-break. fmed3 clamp -> out-of-window degrades to a flagged
// tie (exact cleanup fixes), never silent corruption.
#define CLAMP_HI 159.99998474121094f   // predecessor of 160.0f
#define ULP128 1.52587890625e-5f       // 2^-23 * 128 = T' ULP in-window
// flag threshold: 41 T'-ULPs ~ 6.3e-4. Decision error sigma ~8e-6 (bias
// outside the chain) -> ~75 sigma margin.
#define FLAG_THR (41u << 10)

typedef __attribute__((ext_vector_type(8))) short short8v;   // 8 bf16 (4 VGPRs)
typedef __attribute__((ext_vector_type(4))) float f32x4;

__device__ __forceinline__ unsigned short f2bf_rne(float f) {
  unsigned u = __builtin_bit_cast(unsigned, f);
  u += 0x7FFFu + ((u >> 16) & 1u);
  return (unsigned short)(u >> 16);
}
__device__ __forceinline__ float bf2f(unsigned short h) {
  unsigned u = ((unsigned)h) << 16;
  return __builtin_bit_cast(float, u);
}

// ---------------------------------------------------------------------------
// ws layout (4-byte units):
//   [0, K)                 : counts (uint)
//   [K]                    : sq accum (float)
//   [K+1]                  : flag counter (uint)
//   [K+2, K+4)             : pad
//   [K+4, 2K+4)            : cnorm (float)
//   [2K+4, 3K+4)           : hcn = -0.5*cnorm (float)
//   [3K+4, 3K+4+FLAG_CAP)  : flag list (uint)
//   pk : packed split codebook, K rows x 128 bf16 (hi[64] | lo[64]) = 256 KB
//   cbT: transposed fp32 codebook [D][K] = 256 KB (only if ws_size allows)
// ---------------------------------------------------------------------------

__global__ __launch_bounds__(256) void vq_prep_kernel(
    const float* __restrict__ cb, float* __restrict__ cnorm,
    float* __restrict__ hcn, unsigned short* __restrict__ pk,
    float* __restrict__ cbT, int write_t) {
  int k = blockIdx.x * 256 + threadIdx.x;
  if (k >= K) return;
  const float4* cp = reinterpret_cast<const float4*>(cb + (size_t)k * D);
  unsigned short* row = pk + (size_t)k * 128;
  float s = 0.f;
#pragma unroll
  for (int j4 = 0; j4 < 16; ++j4) {
    float4 v = cp[j4];
    float ff[4] = {v.x, v.y, v.z, v.w};
    ushort4 hh, ll;
    unsigned short* hp = (unsigned short*)&hh;
    unsigned short* lp = (unsigned short*)&ll;
#pragma unroll
    for (int u = 0; u < 4; ++u) {
      float f = ff[u];
      s = fmaf(f, f, s);  // ascending-j fmaf, same order as r1 scan
      unsigned short hb = f2bf_rne(f);
      float lo = f - bf2f(hb);
      hp[u] = hb;
      lp[u] = f2bf_rne(lo);
      if (write_t) cbT[(size_t)(j4 * 4 + u) * K + k] = f;
    }
    reinterpret_cast<ushort4*>(row)[j4] = hh;
    reinterpret_cast<ushort4*>(row + 64)[j4] = ll;
  }
  cnorm[k] = s;
  hcn[k] = -0.5f * s;
}

__device__ __forceinline__ float block_reduce_sum_256(float v) {
#pragma unroll
  for (int o = 32; o > 0; o >>= 1) v += __shfl_down(v, o, 64);
  __shared__ float s[4];
  int lane = threadIdx.x & 63;
  int w = threadIdx.x >> 6;
  if (lane == 0) s[w] = v;
  __syncthreads();
  float r = 0.f;
  if (threadIdx.x == 0) r = s[0] + s[1] + s[2] + s[3];
  return r;  // valid on thread 0 only
}

// r9 structure, 32 rows/wave: 256 threads / 4 waves / 2 row-tiles of 16 per
// wave, grid 2048. Register double-buffer for B (rotation form — compiler
// renames); packed-u32 argmax epilogue, bias outside the MFMA chain; fused sq.
// VGPR target < 96 -> 5 waves/SIMD (r9's 104 -> 4).
__global__ __launch_bounds__(256) void vq_argmin_mfma_kernel(
    const float* __restrict__ x, const unsigned short* __restrict__ pk,
    const float* __restrict__ hcn, float* __restrict__ tok_out,
    unsigned int* __restrict__ counts, float* __restrict__ sq_accum,
    unsigned int* __restrict__ flag_cnt, unsigned int* __restrict__ flag_list) {
  __shared__ unsigned int hist[K];
  for (int i = threadIdx.x; i < K; i += 256) hist[i] = 0u;
  __syncthreads();

  const int lane = threadIdx.x & 63;
  const int w = threadIdx.x >> 6;
  const int c16 = lane & 15;  // A row within tile / B col within tile
  const int g4 = lane >> 4;   // k-group
  const int wave_base = blockIdx.x * 128 + w * 32;

  // A fragments: 2 row-tiles x 2 k-steps x (hi, lo); per-lane |x|^2 partials
  short8v ah[2][2], al[2][2];
  float xx[2];
#pragma unroll
  for (int rt = 0; rt < 2; ++rt) {
    float xp = 0.f;
#pragma unroll
    for (int s = 0; s < 2; ++s) {
      int row = wave_base + rt * 16 + c16;
      const float* p = x + (size_t)row * D + s * 32 + g4 * 8;
      float4 f0 = *(const float4*)(p);
      float4 f1 = *(const float4*)(p + 4);
      float ff[8] = {f0.x, f0.y, f0.z, f0.w, f1.x, f1.y, f1.z, f1.w};
      short8v h, l;
#pragma unroll
      for (int j = 0; j < 8; ++j) {
        xp = fmaf(ff[j], ff[j], xp);
        unsigned short hb = f2bf_rne(ff[j]);
        float lo = ff[j] - bf2f(hb);
        h[j] = (short)hb;
        l[j] = (short)f2bf_rne(lo);
      }
      ah[rt][s] = h;
      al[rt][s] = l;
    }
    // full-row |x|^2: reduce over the 4 lanes sharing c16 (xor 16, 32)
    float t1 = xp + __shfl_xor(xp, 16, 64);
    xx[rt] = t1 + __shfl_xor(t1, 32, 64);
  }

  unsigned bP[2][4], b2P[2][4];
#pragma unroll
  for (int rt = 0; rt < 2; ++rt)
#pragma unroll
    for (int r = 0; r < 4; ++r) {
      bP[rt][r] = 0u;
      b2P[rt][r] = 0u;
    }

  const unsigned short* pbase = pk + (size_t)c16 * 128 + (size_t)g4 * 8;

  // prologue: tile 0 resident in regs
  short8v cb0 = *(const short8v*)(pbase);
  short8v cb1 = *(const short8v*)(pbase + 32);
  short8v cb2 = *(const short8v*)(pbase + 64);
  short8v cb3 = *(const short8v*)(pbase + 96);
  float hcur = hcn[c16];

  for (int t = 0; t < 64; ++t) {
    // prefetch tile t+1 (register double-buffer; hides under 12 MFMAs)
    int tn = (t < 63) ? (t + 1) : 63;
    const unsigned short* pn = pbase + (size_t)tn * 2048;
    short8v nb0 = *(const short8v*)(pn);
    short8v nb1 = *(const short8v*)(pn + 32);
    short8v nb2 = *(const short8v*)(pn + 64);
    short8v nb3 = *(const short8v*)(pn + 96);
    float hnext = hcn[tn * 16 + c16];

    f32x4 cinit = {hcur, hcur, hcur, hcur};  // -0.5|c|^2, small magnitude
    f32x4 zro = {0.f, 0.f, 0.f, 0.f};
    const unsigned pcv = 1023u - (unsigned)(t * 16 + c16);
#pragma unroll
    for (int rt = 0; rt < 2; ++rt) {
      f32x4 a0 = cinit;  // chain over k in [0,32)
      f32x4 a1 = zro;    // chain over k in [32,64)
      a0 = __builtin_amdgcn_mfma_f32_16x16x32_bf16(ah[rt][0], cb0, a0, 0, 0, 0);
      a1 = __builtin_amdgcn_mfma_f32_16x16x32_bf16(ah[rt][1], cb1, a1, 0, 0, 0);
      a0 = __builtin_amdgcn_mfma_f32_16x16x32_bf16(ah[rt][0], cb2, a0, 0, 0, 0);
      a1 = __builtin_amdgcn_mfma_f32_16x16x32_bf16(ah[rt][1], cb3, a1, 0, 0, 0);
      a0 = __builtin_amdgcn_mfma_f32_16x16x32_bf16(al[rt][0], cb0, a0, 0, 0, 0);
      a1 = __builtin_amdgcn_mfma_f32_16x16x32_bf16(al[rt][1], cb1, a1, 0, 0, 0);
#pragma unroll
      for (int r = 0; r < 4; ++r) {
        float T = a0[r] + a1[r];
        float Tb = T + T_BIAS;  // single rounding at ULP(144)
        Tb = __builtin_amdgcn_fmed3f(Tb, 128.0f, CLAMP_HI);  // window guard
        unsigned bits = __builtin_bit_cast(unsigned, Tb);
        unsigned p = (bits << 10) | pcv;  // exact order + lowest-code tie-break
        unsigned mn = p < bP[rt][r] ? p : bP[rt][r];
        bP[rt][r] = p > bP[rt][r] ? p : bP[rt][r];
        b2P[rt][r] = mn > b2P[rt][r] ? mn : b2P[rt][r];
      }
    }
    cb0 = nb0; cb1 = nb1; cb2 = nb2; cb3 = nb3; hcur = hnext;
  }

  float sqloc = 0.f;
  // reduce across the 16 col-lanes of each group; u32 max keeps tie-break
#pragma unroll
  for (int rt = 0; rt < 2; ++rt) {
#pragma unroll
    for (int r = 0; r < 4; ++r) {
      unsigned b = bP[rt][r], b2 = b2P[rt][r];
#pragma unroll
      for (int m = 1; m < 16; m <<= 1) {
        unsigned ob = (unsigned)__shfl_xor((int)b, m, 64);
        unsigned ob2 = (unsigned)__shfl_xor((int)b2, m, 64);
        unsigned mn = b < ob ? b : ob;
        b = b > ob ? b : ob;
        unsigned t2 = b2 > ob2 ? b2 : ob2;
        b2 = t2 > mn ? t2 : mn;
      }
      // row |x|^2 for output row (rt, g4*4+r) lives on lane c16 = g4*4+r
      float xxr = __shfl(xx[rt], g4 * 4 + r, 64);
      if (c16 == 0) {
        int code = 1023 - (int)(b & 1023u);
        int grow = wave_base + rt * 16 + g4 * 4 + r;
        tok_out[grow] = (float)code;
        atomicAdd(&hist[code], 1u);
        // exact T' reconstruction (window keeps mantissa bits 21:0 in b>>10):
        // dist = |x|^2 - 2*(T'-144) = xx + 288 - 2*T'
        float Tt = 128.0f + (float)(b >> 10) * ULP128;
        sqloc += (xxr + 2.0f * T_BIAS) - 2.0f * Tt;
        if (b - b2 < FLAG_THR) {
          unsigned pfl = atomicAdd(flag_cnt, 1u);
          if (pfl < FLAG_CAP) flag_list[pfl] = (unsigned)grow;
        }
      }
    }
  }
  __syncthreads();
  for (int i = threadIdx.x; i < K; i += 256) {
    unsigned h = hist[i];
    if (h) atomicAdd(&counts[i], h);
  }
  float bs = block_reduce_sum_256(sqloc);
  if (threadIdx.x == 0) atomicAdd(sq_accum, bs);
}

// Exact fp32 rescan: ONE BLOCK per flagged vector (coalesced cbT reads,
// ILP-4). Patches token, counts, and the fused sq accumulator.
__global__ __launch_bounds__(256) void vq_cleanup_blk_kernel(
    const float* __restrict__ x, const float* __restrict__ cbT,
    const float* __restrict__ cnorm, float* __restrict__ tok,
    unsigned int* __restrict__ counts, float* __restrict__ sq_accum,
    const unsigned int* __restrict__ flag_cnt,
    const unsigned int* __restrict__ flag_list) {
  __shared__ float xs[D];
  __shared__ float wb[4], wd[4];
  __shared__ int wk[4];
  unsigned nf = *flag_cnt;
  if (nf > FLAG_CAP) nf = FLAG_CAP;
  const int t = threadIdx.x;
  for (unsigned f = blockIdx.x; f < nf; f += gridDim.x) {  // uniform per block
    int vid = (int)flag_list[f];
    int old = (int)tok[vid];
    __syncthreads();  // xs/wb/wk/wd safe to overwrite (prev iter done)
    if (t < D) xs[t] = x[(size_t)vid * D + t];
    __syncthreads();

    float xx = 0.f;
#pragma unroll
    for (int j = 0; j < D; ++j) xx = fmaf(xs[j], xs[j], xx);

    float d0 = 0.f, d1 = 0.f, d2 = 0.f, d3 = 0.f;
#pragma unroll 8
    for (int j = 0; j < D; ++j) {
      float xj = xs[j];
      const float* row = cbT + (size_t)j * K + t;
      d0 = fmaf(xj, row[0], d0);
      d1 = fmaf(xj, row[256], d1);
      d2 = fmaf(xj, row[512], d2);
      d3 = fmaf(xj, row[768], d3);
    }
    float dist0 = (xx + cnorm[t]) - 2.0f * d0;
    float dist1 = (xx + cnorm[t + 256]) - 2.0f * d1;
    float dist2 = (xx + cnorm[t + 512]) - 2.0f * d2;
    float dist3 = (xx + cnorm[t + 768]) - 2.0f * d3;

    // exact distance of the previously-chosen token (for the sq patch)
    float dold = 3.4e38f;
    if ((old & 255) == t) {
      int slot = old >> 8;
      dold = slot == 0 ? dist0 : slot == 1 ? dist1 : slot == 2 ? dist2 : dist3;
    }

    // per-thread best among owned codes (ascending k, strict < => lowest k)
    float best = dist0;
    int bk = t;
    if (dist1 < best) { best = dist1; bk = t + 256; }
    if (dist2 < best) { best = dist2; bk = t + 512; }
    if (dist3 < best) { best = dist3; bk = t + 768; }

#pragma unroll
    for (int m = 1; m < 64; m <<= 1) {
      float ob = __shfl_xor(best, m, 64);
      int oi = __shfl_xor(bk, m, 64);
      bool take = (ob < best) || (ob == best && oi < bk);
      best = take ? ob : best;
      bk = take ? oi : bk;
      dold = fminf(dold, __shfl_xor(dold, m, 64));
    }
    if ((t & 63) == 0) { wb[t >> 6] = best; wk[t >> 6] = bk; wd[t >> 6] = dold; }
    __syncthreads();
    if (t == 0) {
#pragma unroll
      for (int wv = 1; wv < 4; ++wv) {
        bool take = (wb[wv] < best) || (wb[wv] == best && wk[wv] < bk);
        best = take ? wb[wv] : best;
        bk = take ? wk[wv] : bk;
        dold = fminf(dold, wd[wv]);
      }
      if (bk != old) {
        tok[vid] = (float)bk;
        atomicAdd(&counts[old], 0xFFFFFFFFu);  // -1
        atomicAdd(&counts[bk], 1u);
        atomicAdd(sq_accum, best - dold);
      }
    }
  }
}

// Fallback (ws too small for cbT): strided-row rescan with sq patch.
__global__ __launch_bounds__(256) void vq_cleanup_kernel(
    const float* __restrict__ x, const float* __restrict__ cb,
    const float* __restrict__ cnorm, float* __restrict__ tok,
    unsigned int* __restrict__ counts, float* __restrict__ sq_accum,
    const unsigned int* __restrict__ flag_cnt,
    const unsigned int* __restrict__ flag_list) {
  const int lane = threadIdx.x & 63;
  const int gw = blockIdx.x * (blockDim.x >> 6) + (threadIdx.x >> 6);
  const int nw = gridDim.x * (blockDim.x >> 6);
  unsigned nf = *flag_cnt;
  if (nf > FLAG_CAP) nf = FLAG_CAP;
  for (unsigned f = gw; f < nf; f += nw) {
    int vid = (int)flag_list[f];
    int old = (int)tok[vid];
    const float* xv = x + (size_t)vid * D;
    float xr[D];
#pragma unroll
    for (int j = 0; j < 16; ++j) {
      float4 v = ((const float4*)xv)[j];
      xr[4 * j] = v.x; xr[4 * j + 1] = v.y;
      xr[4 * j + 2] = v.z; xr[4 * j + 3] = v.w;
    }
    float xx = 0.f;
#pragma unroll
    for (int j = 0; j < D; ++j) xx = fmaf(xr[j], xr[j], xx);
    float best = 3.4e38f, dold = 3.4e38f;
    int bidx = K;
    for (int i = 0; i < 16; ++i) {
      int k = i * 64 + lane;
      const float* c = cb + (size_t)k * D;
      float acc = 0.f;
#pragma unroll
      for (int j = 0; j < D; ++j) acc = fmaf(xr[j], c[j], acc);
      float dist = (xx + cnorm[k]) - 2.0f * acc;
      if (dist < best) { best = dist; bidx = k; }
      if (k == old) dold = dist;
    }
#pragma unroll
    for (int m = 1; m < 64; m <<= 1) {
      float ob = __shfl_xor(best, m, 64);
      int oi = __shfl_xor(bidx, m, 64);
      bool take = (ob < best) || (ob == best && oi < bidx);
      best = take ? ob : best;
      bidx = take ? oi : bidx;
      dold = fminf(dold, __shfl_xor(dold, m, 64));
    }
    if (lane == 0 && bidx != old) {
      tok[vid] = (float)bidx;
      atomicAdd(&counts[old], 0xFFFFFFFFu);
      atomicAdd(&counts[bidx], 1u);
      atomicAdd(sq_accum, best - dold);
    }
  }
}

// quantized_st forward value == codebook[token]; write-only.
__global__ __launch_bounds__(256) void vq_writeq_kernel(
    const float* __restrict__ cb, const float* __restrict__ tok,
    float* __restrict__ outq) {
  const int total4 = N_VEC * (D / 4);
  for (int idx4 = blockIdx.x * 256 + threadIdx.x; idx4 < total4;
       idx4 += gridDim.x * 256) {
    int vid = idx4 >> 4;
    int j4 = idx4 & 15;
    int t = (int)tok[vid];
    reinterpret_cast<float4*>(outq)[idx4] =
        reinterpret_cast<const float4*>(cb)[t * 16 + j4];
  }
}

__global__ __launch_bounds__(256) void vq_finalize_kernel(
    const unsigned int* __restrict__ counts, const float* __restrict__ sq_accum,
    float* __restrict__ out_scalars) {
  float h = 0.f;
  for (int i = threadIdx.x; i < K; i += 256) {
    float p = (float)counts[i] / (float)N_VEC;
    h -= p * logf(p + 1e-10f);
  }
  float hs = block_reduce_sum_256(h);
  if (threadIdx.x == 0) {
    float m = sq_accum[0] / (float)((size_t)N_VEC * D);
    out_scalars[0] = 1.25f * m;  // vq_loss
    out_scalars[1] = 0.25f * m;  // commitment_loss
    out_scalars[2] = m;          // codebook_loss
    out_scalars[3] = expf(hs);   // perplexity
  }
}

extern "C" void kernel_launch(void* const* d_in, const int* in_sizes, int n_in,
                              void* d_out, int out_size, void* d_ws,
                              size_t ws_size, hipStream_t stream) {
  const float* x = (const float*)d_in[0];
  const float* cb = (const float*)d_in[1];

  float* outq = (float*)d_out;
  float* tok = outq + (size_t)N_VEC * D;
  float* scal = tok + N_VEC;

  unsigned int* counts = (unsigned int*)d_ws;                 // K
  float* sq = (float*)d_ws + K;                               // 1
  unsigned int* flag_cnt = (unsigned int*)d_ws + K + 1;       // 1
  float* cnorm = (float*)d_ws + K + 4;                        // K
  float* hcn = (float*)d_ws + 2 * K + 4;                      // K
  unsigned int* flag_list = (unsigned int*)d_ws + 3 * K + 4;  // FLAG_CAP
  size_t base_dw = (size_t)3 * K + 4 + FLAG_CAP;
  unsigned short* pk = (unsigned short*)((unsigned int*)d_ws + base_dw);
  size_t pk_dw = (size_t)K * 128 / 2;  // 65536 dwords
  float* cbT = (float*)((unsigned int*)d_ws + base_dw + pk_dw);
  size_t need_t = (base_dw + pk_dw + (size_t)K * D) * 4;
  int use_t = (ws_size >= need_t) ? 1 : 0;

  // zero counts + sq + flag counter every call
  hipMemsetAsync(d_ws, 0, (size_t)(K + 2) * sizeof(float), stream);

  vq_prep_kernel<<<(K + 255) / 256, 256, 0, stream>>>(cb, cnorm, hcn, pk, cbT,
                                                      use_t);
  vq_argmin_mfma_kernel<<<N_VEC / 128, 256, 0, stream>>>(
      x, pk, hcn, tok, counts, sq, flag_cnt, flag_list);
  if (use_t) {
    vq_cleanup_blk_kernel<<<2048, 256, 0, stream>>>(x, cbT, cnorm, tok, counts,
                                                    sq, flag_cnt, flag_list);
  } else {
    vq_cleanup_kernel<<<1024, 256, 0, stream>>>(x, cb, cnorm, tok, counts, sq,
                                                flag_cnt, flag_list);
  }
  vq_writeq_kernel<<<4096, 256, 0, stream>>>(cb, tok, outq);
  vq_finalize_kernel<<<1, 256, 0, stream>>>(counts, sq, scal);
}

// Round 13
// 214.295 us; speedup vs baseline: 1.6602x; 1.6602x over previous
//
#include <hip/hip_runtime.h>
#include <hip/hip_bf16.h>
#include <math.h>

#define D 64
#define K 1024
#define N_VEC 262144  // 64*64*64
#define FLAG_CAP 65536
#define T_BIAS 144.0f
// Accumulate T = x.c - 0.5|c|^2 at natural magnitude (|acc| <~ 6, adds round
// at ~2.4e-7), then add T_BIAS=144 ONCE per element. T' in (137,151) within
// window [128,160): bits[31:22] constant (exp 134, mantissa bit22=0), so
// packed = (bits<<10)|(1023-code) is exact order-preserving u32 with
// lowest-code tie-break. fmed3 clamp -> out-of-window degrades to a flagged
// tie (exact cleanup fixes), never silent corruption.
#define CLAMP_HI 159.99998474121094f   // predecessor of 160.0f
#define ULP128 1.52587890625e-5f       // 2^-23 * 128 = T' ULP in-window
// flag threshold: 41 T'-ULPs ~ 6.3e-4. Decision error sigma ~8e-6 (bias now
// outside the chain) -> ~75 sigma margin.
#define FLAG_THR (41u << 10)

typedef __attribute__((ext_vector_type(8))) short short8v;   // 8 bf16 (4 VGPRs)
typedef __attribute__((ext_vector_type(4))) float f32x4;

__device__ __forceinline__ unsigned short f2bf_rne(float f) {
  unsigned u = __builtin_bit_cast(unsigned, f);
  u += 0x7FFFu + ((u >> 16) & 1u);
  return (unsigned short)(u >> 16);
}
__device__ __forceinline__ float bf2f(unsigned short h) {
  unsigned u = ((unsigned)h) << 16;
  return __builtin_bit_cast(float, u);
}

// ---------------------------------------------------------------------------
// ws layout (4-byte units):
//   [0, K)                 : counts (uint)
//   [K]                    : sq accum (float)
//   [K+1]                  : flag counter (uint)
//   [K+2, K+4)             : pad
//   [K+4, 2K+4)            : cnorm (float)
//   [2K+4, 3K+4)           : hcn = -0.5*cnorm (float)
//   [3K+4, 3K+4+FLAG_CAP)  : flag list (uint)
//   pk : packed split codebook, K rows x 128 bf16 (hi[64] | lo[64]) = 256 KB
//   cbT: transposed fp32 codebook [D][K] = 256 KB (only if ws_size allows)
// ---------------------------------------------------------------------------

__global__ __launch_bounds__(256) void vq_prep_kernel(
    const float* __restrict__ cb, float* __restrict__ cnorm,
    float* __restrict__ hcn, unsigned short* __restrict__ pk,
    float* __restrict__ cbT, int write_t) {
  int k = blockIdx.x * 256 + threadIdx.x;
  if (k >= K) return;
  const float4* cp = reinterpret_cast<const float4*>(cb + (size_t)k * D);
  unsigned short* row = pk + (size_t)k * 128;
  float s = 0.f;
#pragma unroll
  for (int j4 = 0; j4 < 16; ++j4) {
    float4 v = cp[j4];
    float ff[4] = {v.x, v.y, v.z, v.w};
    ushort4 hh, ll;
    unsigned short* hp = (unsigned short*)&hh;
    unsigned short* lp = (unsigned short*)&ll;
#pragma unroll
    for (int u = 0; u < 4; ++u) {
      float f = ff[u];
      s = fmaf(f, f, s);  // ascending-j fmaf, same order as r1 scan
      unsigned short hb = f2bf_rne(f);
      float lo = f - bf2f(hb);
      hp[u] = hb;
      lp[u] = f2bf_rne(lo);
      if (write_t) cbT[(size_t)(j4 * 4 + u) * K + k] = f;
    }
    reinterpret_cast<ushort4*>(row)[j4] = hh;
    reinterpret_cast<ushort4*>(row + 64)[j4] = ll;
  }
  cnorm[k] = s;
  hcn[k] = -0.5f * s;
}

__device__ __forceinline__ float block_reduce_sum_256(float v) {
#pragma unroll
  for (int o = 32; o > 0; o >>= 1) v += __shfl_down(v, o, 64);
  __shared__ float s[4];
  int lane = threadIdx.x & 63;
  int w = threadIdx.x >> 6;
  if (lane == 0) s[w] = v;
  __syncthreads();
  float r = 0.f;
  if (threadIdx.x == 0) r = s[0] + s[1] + s[2] + s[3];
  return r;  // valid on thread 0 only
}

// 256 threads / 4 waves / 64 rows per wave (4 row-tiles of 16), grid 1024.
// Register double-buffer for B; packed-u32 argmax epilogue with the bias
// OUTSIDE the MFMA chain; fused sq (best-dist accumulation).
__global__ __launch_bounds__(256) void vq_argmin_mfma_kernel(
    const float* __restrict__ x, const unsigned short* __restrict__ pk,
    const float* __restrict__ hcn, float* __restrict__ tok_out,
    unsigned int* __restrict__ counts, float* __restrict__ sq_accum,
    unsigned int* __restrict__ flag_cnt, unsigned int* __restrict__ flag_list) {
  __shared__ unsigned int hist[K];
  for (int i = threadIdx.x; i < K; i += 256) hist[i] = 0u;
  __syncthreads();

  const int lane = threadIdx.x & 63;
  const int w = threadIdx.x >> 6;
  const int c16 = lane & 15;  // A row within tile / B col within tile
  const int g4 = lane >> 4;   // k-group
  const int wave_base = blockIdx.x * 256 + w * 64;

  // A fragments: 4 row-tiles x 2 k-steps x (hi, lo); per-lane |x|^2 partials
  short8v ah[4][2], al[4][2];
  float xx[4];
#pragma unroll
  for (int rt = 0; rt < 4; ++rt) {
    float xp = 0.f;
#pragma unroll
    for (int s = 0; s < 2; ++s) {
      int row = wave_base + rt * 16 + c16;
      const float* p = x + (size_t)row * D + s * 32 + g4 * 8;
      float4 f0 = *(const float4*)(p);
      float4 f1 = *(const float4*)(p + 4);
      float ff[8] = {f0.x, f0.y, f0.z, f0.w, f1.x, f1.y, f1.z, f1.w};
      short8v h, l;
#pragma unroll
      for (int j = 0; j < 8; ++j) {
        xp = fmaf(ff[j], ff[j], xp);
        unsigned short hb = f2bf_rne(ff[j]);
        float lo = ff[j] - bf2f(hb);
        h[j] = (short)hb;
        l[j] = (short)f2bf_rne(lo);
      }
      ah[rt][s] = h;
      al[rt][s] = l;
    }
    // full-row |x|^2: reduce over the 4 lanes sharing c16 (xor 16, 32)
    float t1 = xp + __shfl_xor(xp, 16, 64);
    xx[rt] = t1 + __shfl_xor(t1, 32, 64);
  }

  unsigned bP[4][4], b2P[4][4];
#pragma unroll
  for (int rt = 0; rt < 4; ++rt)
#pragma unroll
    for (int r = 0; r < 4; ++r) {
      bP[rt][r] = 0u;
      b2P[rt][r] = 0u;
    }

  const unsigned short* pbase = pk + (size_t)c16 * 128 + (size_t)g4 * 8;

  // prologue: tile 0 resident in regs
  short8v cb0 = *(const short8v*)(pbase);
  short8v cb1 = *(const short8v*)(pbase + 32);
  short8v cb2 = *(const short8v*)(pbase + 64);
  short8v cb3 = *(const short8v*)(pbase + 96);
  float hcur = hcn[c16];

  for (int t = 0; t < 64; ++t) {
    // prefetch tile t+1 (register double-buffer; hides under 24 MFMAs)
    int tn = (t < 63) ? (t + 1) : 63;
    const unsigned short* pn = pbase + (size_t)tn * 2048;
    short8v nb0 = *(const short8v*)(pn);
    short8v nb1 = *(const short8v*)(pn + 32);
    short8v nb2 = *(const short8v*)(pn + 64);
    short8v nb3 = *(const short8v*)(pn + 96);
    float hnext = hcn[tn * 16 + c16];

    f32x4 cinit = {hcur, hcur, hcur, hcur};  // -0.5|c|^2, small magnitude
    f32x4 zro = {0.f, 0.f, 0.f, 0.f};
    const unsigned pcv = 1023u - (unsigned)(t * 16 + c16);
#pragma unroll
    for (int rt = 0; rt < 4; ++rt) {
      f32x4 a0 = cinit;  // chain over k in [0,32)
      f32x4 a1 = zro;    // chain over k in [32,64)
      a0 = __builtin_amdgcn_mfma_f32_16x16x32_bf16(ah[rt][0], cb0, a0, 0, 0, 0);
      a1 = __builtin_amdgcn_mfma_f32_16x16x32_bf16(ah[rt][1], cb1, a1, 0, 0, 0);
      a0 = __builtin_amdgcn_mfma_f32_16x16x32_bf16(ah[rt][0], cb2, a0, 0, 0, 0);
      a1 = __builtin_amdgcn_mfma_f32_16x16x32_bf16(ah[rt][1], cb3, a1, 0, 0, 0);
      a0 = __builtin_amdgcn_mfma_f32_16x16x32_bf16(al[rt][0], cb0, a0, 0, 0, 0);
      a1 = __builtin_amdgcn_mfma_f32_16x16x32_bf16(al[rt][1], cb1, a1, 0, 0, 0);
#pragma unroll
      for (int r = 0; r < 4; ++r) {
        float T = a0[r] + a1[r];
        float Tb = T + T_BIAS;  // single rounding at ULP(144)
        Tb = __builtin_amdgcn_fmed3f(Tb, 128.0f, CLAMP_HI);  // window guard
        unsigned bits = __builtin_bit_cast(unsigned, Tb);
        unsigned p = (bits << 10) | pcv;  // exact order + lowest-code tie-break
        unsigned mn = p < bP[rt][r] ? p : bP[rt][r];
        bP[rt][r] = p > bP[rt][r] ? p : bP[rt][r];
        b2P[rt][r] = mn > b2P[rt][r] ? mn : b2P[rt][r];
      }
    }
    cb0 = nb0; cb1 = nb1; cb2 = nb2; cb3 = nb3; hcur = hnext;
  }

  float sqloc = 0.f;
  // reduce across the 16 col-lanes of each group; u32 max keeps tie-break
#pragma unroll
  for (int rt = 0; rt < 4; ++rt) {
#pragma unroll
    for (int r = 0; r < 4; ++r) {
      unsigned b = bP[rt][r], b2 = b2P[rt][r];
#pragma unroll
      for (int m = 1; m < 16; m <<= 1) {
        unsigned ob = (unsigned)__shfl_xor((int)b, m, 64);
        unsigned ob2 = (unsigned)__shfl_xor((int)b2, m, 64);
        unsigned mn = b < ob ? b : ob;
        b = b > ob ? b : ob;
        unsigned t2 = b2 > ob2 ? b2 : ob2;
        b2 = t2 > mn ? t2 : mn;
      }
      // row |x|^2 for output row (rt, g4*4+r) lives on lane c16 = g4*4+r
      float xxr = __shfl(xx[rt], g4 * 4 + r, 64);
      if (c16 == 0) {
        int code = 1023 - (int)(b & 1023u);
        int grow = wave_base + rt * 16 + g4 * 4 + r;
        tok_out[grow] = (float)code;
        atomicAdd(&hist[code], 1u);
        // exact T' reconstruction (window keeps mantissa bits 21:0 in b>>10):
        // dist = |x|^2 - 2*(T'-144) = xx + 288 - 2*T'
        float Tt = 128.0f + (float)(b >> 10) * ULP128;
        sqloc += (xxr + 2.0f * T_BIAS) - 2.0f * Tt;
        if (b - b2 < FLAG_THR) {
          unsigned pfl = atomicAdd(flag_cnt, 1u);
          if (pfl < FLAG_CAP) flag_list[pfl] = (unsigned)grow;
        }
      }
    }
  }
  __syncthreads();
  for (int i = threadIdx.x; i < K; i += 256) {
    unsigned h = hist[i];
    if (h) atomicAdd(&counts[i], h);
  }
  float bs = block_reduce_sum_256(sqloc);
  if (threadIdx.x == 0) atomicAdd(sq_accum, bs);
}

// Exact fp32 rescan: ONE BLOCK per flagged vector (coalesced cbT reads,
// ILP-4). Patches token, counts, and the fused sq accumulator.
__global__ __launch_bounds__(256) void vq_cleanup_blk_kernel(
    const float* __restrict__ x, const float* __restrict__ cbT,
    const float* __restrict__ cnorm, float* __restrict__ tok,
    unsigned int* __restrict__ counts, float* __restrict__ sq_accum,
    const unsigned int* __restrict__ flag_cnt,
    const unsigned int* __restrict__ flag_list) {
  __shared__ float xs[D];
  __shared__ float wb[4], wd[4];
  __shared__ int wk[4];
  unsigned nf = *flag_cnt;
  if (nf > FLAG_CAP) nf = FLAG_CAP;
  const int t = threadIdx.x;
  for (unsigned f = blockIdx.x; f < nf; f += gridDim.x) {  // uniform per block
    int vid = (int)flag_list[f];
    int old = (int)tok[vid];
    __syncthreads();  // xs/wb/wk/wd safe to overwrite (prev iter done)
    if (t < D) xs[t] = x[(size_t)vid * D + t];
    __syncthreads();

    float xx = 0.f;
#pragma unroll
    for (int j = 0; j < D; ++j) xx = fmaf(xs[j], xs[j], xx);

    float d0 = 0.f, d1 = 0.f, d2 = 0.f, d3 = 0.f;
#pragma unroll 8
    for (int j = 0; j < D; ++j) {
      float xj = xs[j];
      const float* row = cbT + (size_t)j * K + t;
      d0 = fmaf(xj, row[0], d0);
      d1 = fmaf(xj, row[256], d1);
      d2 = fmaf(xj, row[512], d2);
      d3 = fmaf(xj, row[768], d3);
    }
    float dist0 = (xx + cnorm[t]) - 2.0f * d0;
    float dist1 = (xx + cnorm[t + 256]) - 2.0f * d1;
    float dist2 = (xx + cnorm[t + 512]) - 2.0f * d2;
    float dist3 = (xx + cnorm[t + 768]) - 2.0f * d3;

    // exact distance of the previously-chosen token (for the sq patch)
    float dold = 3.4e38f;
    if ((old & 255) == t) {
      int slot = old >> 8;
      dold = slot == 0 ? dist0 : slot == 1 ? dist1 : slot == 2 ? dist2 : dist3;
    }

    // per-thread best among owned codes (ascending k, strict < => lowest k)
    float best = dist0;
    int bk = t;
    if (dist1 < best) { best = dist1; bk = t + 256; }
    if (dist2 < best) { best = dist2; bk = t + 512; }
    if (dist3 < best) { best = dist3; bk = t + 768; }

#pragma unroll
    for (int m = 1; m < 64; m <<= 1) {
      float ob = __shfl_xor(best, m, 64);
      int oi = __shfl_xor(bk, m, 64);
      bool take = (ob < best) || (ob == best && oi < bk);
      best = take ? ob : best;
      bk = take ? oi : bk;
      dold = fminf(dold, __shfl_xor(dold, m, 64));
    }
    if ((t & 63) == 0) { wb[t >> 6] = best; wk[t >> 6] = bk; wd[t >> 6] = dold; }
    __syncthreads();
    if (t == 0) {
#pragma unroll
      for (int wv = 1; wv < 4; ++wv) {
        bool take = (wb[wv] < best) || (wb[wv] == best && wk[wv] < bk);
        best = take ? wb[wv] : best;
        bk = take ? wk[wv] : bk;
        dold = fminf(dold, wd[wv]);
      }
      if (bk != old) {
        tok[vid] = (float)bk;
        atomicAdd(&counts[old], 0xFFFFFFFFu);  // -1
        atomicAdd(&counts[bk], 1u);
        atomicAdd(sq_accum, best - dold);
      }
    }
  }
}

// Fallback (ws too small for cbT): strided-row rescan with sq patch.
__global__ __launch_bounds__(256) void vq_cleanup_kernel(
    const float* __restrict__ x, const float* __restrict__ cb,
    const float* __restrict__ cnorm, float* __restrict__ tok,
    unsigned int* __restrict__ counts, float* __restrict__ sq_accum,
    const unsigned int* __restrict__ flag_cnt,
    const unsigned int* __restrict__ flag_list) {
  const int lane = threadIdx.x & 63;
  const int gw = blockIdx.x * (blockDim.x >> 6) + (threadIdx.x >> 6);
  const int nw = gridDim.x * (blockDim.x >> 6);
  unsigned nf = *flag_cnt;
  if (nf > FLAG_CAP) nf = FLAG_CAP;
  for (unsigned f = gw; f < nf; f += nw) {
    int vid = (int)flag_list[f];
    int old = (int)tok[vid];
    const float* xv = x + (size_t)vid * D;
    float xr[D];
#pragma unroll
    for (int j = 0; j < 16; ++j) {
      float4 v = ((const float4*)xv)[j];
      xr[4 * j] = v.x; xr[4 * j + 1] = v.y;
      xr[4 * j + 2] = v.z; xr[4 * j + 3] = v.w;
    }
    float xx = 0.f;
#pragma unroll
    for (int j = 0; j < D; ++j) xx = fmaf(xr[j], xr[j], xx);
    float best = 3.4e38f, dold = 3.4e38f;
    int bidx = K;
    for (int i = 0; i < 16; ++i) {
      int k = i * 64 + lane;
      const float* c = cb + (size_t)k * D;
      float acc = 0.f;
#pragma unroll
      for (int j = 0; j < D; ++j) acc = fmaf(xr[j], c[j], acc);
      float dist = (xx + cnorm[k]) - 2.0f * acc;
      if (dist < best) { best = dist; bidx = k; }
      if (k == old) dold = dist;
    }
#pragma unroll
    for (int m = 1; m < 64; m <<= 1) {
      float ob = __shfl_xor(best, m, 64);
      int oi = __shfl_xor(bidx, m, 64);
      bool take = (ob < best) || (ob == best && oi < bidx);
      best = take ? ob : best;
      bidx = take ? oi : bidx;
      dold = fminf(dold, __shfl_xor(dold, m, 64));
    }
    if (lane == 0 && bidx != old) {
      tok[vid] = (float)bidx;
      atomicAdd(&counts[old], 0xFFFFFFFFu);
      atomicAdd(&counts[bidx], 1u);
      atomicAdd(sq_accum, best - dold);
    }
  }
}

// quantized_st forward value == codebook[token] (x + (q-x) to ~1 ULP;
// threshold is 2% of max). Write-only: no 64 MB x re-read.
__global__ __launch_bounds__(256) void vq_writeq_kernel(
    const float* __restrict__ cb, const float* __restrict__ tok,
    float* __restrict__ outq) {
  const int total4 = N_VEC * (D / 4);
  for (int idx4 = blockIdx.x * 256 + threadIdx.x; idx4 < total4;
       idx4 += gridDim.x * 256) {
    int vid = idx4 >> 4;
    int j4 = idx4 & 15;
    int t = (int)tok[vid];
    reinterpret_cast<float4*>(outq)[idx4] =
        reinterpret_cast<const float4*>(cb)[t * 16 + j4];
  }
}

__global__ __launch_bounds__(256) void vq_finalize_kernel(
    const unsigned int* __restrict__ counts, const float* __restrict__ sq_accum,
    float* __restrict__ out_scalars) {
  float h = 0.f;
  for (int i = threadIdx.x; i < K; i += 256) {
    float p = (float)counts[i] / (float)N_VEC;
    h -= p * logf(p + 1e-10f);
  }
  float hs = block_reduce_sum_256(h);
  if (threadIdx.x == 0) {
    float m = sq_accum[0] / (float)((size_t)N_VEC * D);
    out_scalars[0] = 1.25f * m;  // vq_loss
    out_scalars[1] = 0.25f * m;  // commitment_loss
    out_scalars[2] = m;          // codebook_loss
    out_scalars[3] = expf(hs);   // perplexity
  }
}

extern "C" void kernel_launch(void* const* d_in, const int* in_sizes, int n_in,
                              void* d_out, int out_size, void* d_ws,
                              size_t ws_size, hipStream_t stream) {
  const float* x = (const float*)d_in[0];
  const float* cb = (const float*)d_in[1];

  float* outq = (float*)d_out;
  float* tok = outq + (size_t)N_VEC * D;
  float* scal = tok + N_VEC;

  unsigned int* counts = (unsigned int*)d_ws;                 // K
  float* sq = (float*)d_ws + K;                               // 1
  unsigned int* flag_cnt = (unsigned int*)d_ws + K + 1;       // 1
  float* cnorm = (float*)d_ws + K + 4;                        // K
  float* hcn = (float*)d_ws + 2 * K + 4;                      // K
  unsigned int* flag_list = (unsigned int*)d_ws + 3 * K + 4;  // FLAG_CAP
  size_t base_dw = (size_t)3 * K + 4 + FLAG_CAP;
  unsigned short* pk = (unsigned short*)((unsigned int*)d_ws + base_dw);
  size_t pk_dw = (size_t)K * 128 / 2;  // 65536 dwords
  float* cbT = (float*)((unsigned int*)d_ws + base_dw + pk_dw);
  size_t need_t = (base_dw + pk_dw + (size_t)K * D) * 4;
  int use_t = (ws_size >= need_t) ? 1 : 0;

  // zero counts + sq + flag counter every call
  hipMemsetAsync(d_ws, 0, (size_t)(K + 2) * sizeof(float), stream);

  vq_prep_kernel<<<(K + 255) / 256, 256, 0, stream>>>(cb, cnorm, hcn, pk, cbT,
                                                      use_t);
  vq_argmin_mfma_kernel<<<N_VEC / 256, 256, 0, stream>>>(
      x, pk, hcn, tok, counts, sq, flag_cnt, flag_list);
  if (use_t) {
    vq_cleanup_blk_kernel<<<2048, 256, 0, stream>>>(x, cbT, cnorm, tok, counts,
                                                    sq, flag_cnt, flag_list);
  } else {
    vq_cleanup_kernel<<<1024, 256, 0, stream>>>(x, cb, cnorm, tok, counts, sq,
                                                flag_cnt, flag_list);
  }
  vq_writeq_kernel<<<4096, 256, 0, stream>>>(cb, tok, outq);
  vq_finalize_kernel<<<1, 256, 0, stream>>>(counts, sq, scal);
}